// Round 2
// baseline (8921.181 us; speedup 1.0000x reference)
//
#include <hip/hip_runtime.h>
#include <hip/hip_bf16.h>
#include <cstdio>

typedef unsigned short ushort_t;

#define FL   160000      // final sequence length
#define L0   165110      // causal conv output length
#define LSTR 165120      // row stride for residual buffers (multiple of 64)
#define NL   45
#define CHUNKW 40960     // GEMM column-chunk width (320 tiles of 128)

__device__ __forceinline__ float bfu(unsigned int u) { return __uint_as_float(u); }

__device__ __forceinline__ void load8(const float* p, float v[8]) {
    float4 a = ((const float4*)p)[0];
    float4 b = ((const float4*)p)[1];
    v[0]=a.x; v[1]=a.y; v[2]=a.z; v[3]=a.w;
    v[4]=b.x; v[5]=b.y; v[6]=b.z; v[7]=b.w;
}

__device__ __forceinline__ void load8(const ushort_t* p, float v[8]) {
    uint4 r = *(const uint4*)p;
    v[0]=bfu(r.x<<16); v[1]=bfu(r.x&0xffff0000u);
    v[2]=bfu(r.y<<16); v[3]=bfu(r.y&0xffff0000u);
    v[4]=bfu(r.z<<16); v[5]=bfu(r.z&0xffff0000u);
    v[6]=bfu(r.w<<16); v[7]=bfu(r.w&0xffff0000u);
}

__device__ __forceinline__ float tanh_fast(float x) {
    float ax = fabsf(x);
    float e  = __expf(-2.f * ax);
    float r  = (1.f - e) / (1.f + e);
    return copysignf(r, x);
}

// ---------------------------------------------------------------------------
// Causal conv: y[oc][t] = b[oc] + sum_k w[oc][k] * x[t+k],  t < L0
// ---------------------------------------------------------------------------
__global__ __launch_bounds__(256) void causal_kernel(
    const float* __restrict__ x, const float* __restrict__ wc,
    const float* __restrict__ bc, float* __restrict__ y)
{
    __shared__ float ws_[33 * 32];
    __shared__ float bs_[32];
    const int tid = threadIdx.x;
    for (int idx = tid; idx < 33 * 32; idx += 256) {
        int k = idx >> 5, oc = idx & 31;
        ws_[idx] = wc[oc * 33 + k];             // [k][oc]
    }
    if (tid < 32) bs_[tid] = bc[tid];
    __syncthreads();
    const int t = blockIdx.x * 256 + tid;
    if (t >= L0) return;
    float acc[32];
#pragma unroll
    for (int oc = 0; oc < 32; ++oc) acc[oc] = bs_[oc];
    for (int k = 0; k < 33; ++k) {
        float xv = x[t + k];
        const float* wp = &ws_[k * 32];
#pragma unroll
        for (int oc = 0; oc < 32; ++oc) acc[oc] += wp[oc] * xv;
    }
#pragma unroll
    for (int oc = 0; oc < 32; ++oc) y[(size_t)oc * LSTR + t] = acc[oc];
}

// ---------------------------------------------------------------------------
// Fused gate (tanh*sigmoid) + dense + residual. Writes bf16 skip-window slab.
// ---------------------------------------------------------------------------
__global__ __launch_bounds__(256) void gate_dense_kernel(
    const float* __restrict__ xc, float* __restrict__ xn,
    __hip_bfloat16* __restrict__ xslot,
    const float* __restrict__ wt, const float* __restrict__ wsg,
    const float* __restrict__ wd, const float* __restrict__ bt,
    const float* __restrict__ bs, const float* __restrict__ bd,
    int d, int Lout, int S)
{
    __shared__ float w8[32 * 32 * 8];   // [oc][ic][wt0,ws0,wt1,ws1,wt2,ws2,pad,pad]
    __shared__ float wds[1024];         // [oc][ic]
    __shared__ float bts[32], bss[32], bds[32];
    const int tid = threadIdx.x;
    for (int idx = tid; idx < 1024; idx += 256) {
        int g = idx * 3;                // (oc*32+ic)*3
        float* p = &w8[idx * 8];
        p[0] = wt[g];     p[1] = wsg[g];
        p[2] = wt[g + 1]; p[3] = wsg[g + 1];
        p[4] = wt[g + 2]; p[5] = wsg[g + 2];
        wds[idx] = wd[idx];
    }
    if (tid < 32) { bts[tid] = bt[tid]; bss[tid] = bs[tid]; bds[tid] = bd[tid]; }
    __syncthreads();
    const int t = blockIdx.x * 256 + tid;
    if (t >= Lout) return;

    float a[32], s[32];
#pragma unroll
    for (int oc = 0; oc < 32; ++oc) { a[oc] = bts[oc]; s[oc] = bss[oc]; }

    for (int ic = 0; ic < 32; ++ic) {
        const float* xr = xc + (size_t)ic * LSTR + t;
        float x0 = xr[0], x1 = xr[d], x2 = xr[2 * d];
        const float* wp = &w8[ic * 8];  // oc stride = 256 floats
#pragma unroll
        for (int oc = 0; oc < 32; ++oc) {
            const float4 w0 = *(const float4*)(wp + oc * 256);
            const float2 w1 = *(const float2*)(wp + oc * 256 + 4);
            a[oc] += w0.x * x0 + w0.z * x1 + w1.x * x2;
            s[oc] += w0.y * x0 + w0.w * x1 + w1.y * x2;
        }
    }
#pragma unroll
    for (int oc = 0; oc < 32; ++oc) {
        float th = tanh_fast(a[oc]);
        float sg = 1.f / (1.f + __expf(-s[oc]));
        a[oc] = th * sg;                // a[] now holds gated xg
    }
    if (t >= S && t < S + FL) {
        const int tw = t - S;
#pragma unroll
        for (int ic = 0; ic < 32; ++ic)
            xslot[(size_t)ic * FL + tw] = __float2bfloat16(a[ic]);
    }
#pragma unroll
    for (int oc = 0; oc < 32; ++oc) {
        float o = bds[oc] + xc[(size_t)oc * LSTR + t + d];
#pragma unroll
        for (int ic = 0; ic < 32; ++ic) o += wds[oc * 32 + ic] * a[ic];
        xn[(size_t)oc * LSTR + t] = o;
    }
}

// ---------------------------------------------------------------------------
// Generic 128x128 tiled GEMM, fp32 accumulate:  C = op(A @ op(B)) + bias
// A: M x K row-major (TA = float | ushort_t/bf16), B: K x N row-major.
// ---------------------------------------------------------------------------
template<typename TA, typename TB, bool BRELU, bool OUTRELU>
__global__ __launch_bounds__(256) void gemm128(
    const TA* __restrict__ A, int lda,
    const TB* __restrict__ B, int ldb,
    float* __restrict__ C, int ldc,
    const float* __restrict__ bias, int K)
{
    __shared__ float As[16][128];
    __shared__ float Bs[16][128];
    const int tid = threadIdx.x;
    const int n0 = blockIdx.x * 128;
    const int m0 = blockIdx.y * 128;
    const int arow = tid >> 1,  acol = (tid & 1) * 8;
    const int brow = tid >> 4,  bcol = (tid & 15) * 8;
    const int mt = (tid >> 4) * 8, nt = (tid & 15) * 8;
    float acc[8][8] = {};

    for (int k0 = 0; k0 < K; k0 += 16) {
        float av[8], bv[8];
        load8(A + (size_t)(m0 + arow) * lda + (k0 + acol), av);
        load8(B + (size_t)(k0 + brow) * ldb + (n0 + bcol), bv);
        if (BRELU) {
#pragma unroll
            for (int j = 0; j < 8; ++j) bv[j] = fmaxf(bv[j], 0.f);
        }
        __syncthreads();
#pragma unroll
        for (int j = 0; j < 8; ++j) As[acol + j][arow] = av[j];
#pragma unroll
        for (int j = 0; j < 8; ++j) Bs[brow][bcol + j] = bv[j];
        __syncthreads();
#pragma unroll
        for (int kk = 0; kk < 16; ++kk) {
            float a[8], b[8];
#pragma unroll
            for (int i = 0; i < 8; ++i) a[i] = As[kk][mt + i];
#pragma unroll
            for (int j = 0; j < 8; ++j) b[j] = Bs[kk][nt + j];
#pragma unroll
            for (int i = 0; i < 8; ++i)
#pragma unroll
                for (int j = 0; j < 8; ++j) acc[i][j] += a[i] * b[j];
        }
    }
#pragma unroll
    for (int i = 0; i < 8; ++i) {
        const int m = m0 + mt + i;
        const float bi = bias[m];
#pragma unroll
        for (int j = 0; j < 8; ++j) {
            float v = acc[i][j] + bi;
            if (OUTRELU) v = fmaxf(v, 0.f);
            C[(size_t)m * ldc + (n0 + nt + j)] = v;
        }
    }
}

// ---------------------------------------------------------------------------
// Repack skip weights to [oc][l*32+ic] bf16 and sum skip biases over layers.
// ---------------------------------------------------------------------------
__global__ __launch_bounds__(256) void repack_kernel(
    const float* __restrict__ wskip, const float* __restrict__ bskip,
    __hip_bfloat16* __restrict__ wcat, float* __restrict__ bsum)
{
    const int idx = blockIdx.x * 256 + threadIdx.x;
    if (idx < 512 * 1440) {
        int oc = idx / 1440, lic = idx % 1440;
        int l = lic >> 5, ic = lic & 31;
        wcat[idx] = __float2bfloat16(wskip[((size_t)l * 512 + oc) * 32 + ic]);
    }
    if (idx < 512) {
        float s = 0.f;
        for (int l = 0; l < NL; ++l) s += bskip[l * 512 + idx];
        bsum[idx] = s;
    }
}

extern "C" void kernel_launch(void* const* d_in, const int* in_sizes, int n_in,
                              void* d_out, int out_size, void* d_ws, size_t ws_size,
                              hipStream_t stream)
{
    const float* x        = (const float*)d_in[0];
    const float* w_causal = (const float*)d_in[1];
    const float* b_causal = (const float*)d_in[2];
    const float* w_tanh   = (const float*)d_in[3];
    const float* b_tanh   = (const float*)d_in[4];
    const float* w_sig    = (const float*)d_in[5];
    const float* b_sig    = (const float*)d_in[6];
    const float* w_skip   = (const float*)d_in[7];
    const float* b_skip   = (const float*)d_in[8];
    const float* w_dense  = (const float*)d_in[9];
    const float* b_dense  = (const float*)d_in[10];
    const float* w_post1  = (const float*)d_in[11];
    const float* b_post1  = (const float*)d_in[12];
    const float* w_post2  = (const float*)d_in[13];
    const float* b_post2  = (const float*)d_in[14];
    float* out = (float*)d_out;

    // Workspace carve (bytes, all 16B aligned). Budget: ws_size = 655,360,000.
    //   Xcat  bf16 1440 x FL     : 460,800,000  [0 .. 460,800,000)
    //   skipc fp32  512 x CHUNKW :  83,886,080  [460,800,000 .. 544,686,080)
    //   hc    fp32  512 x CHUNKW :  83,886,080  [544,686,080 .. 628,572,160)
    //   wcat  bf16  512 x 1440   :   1,474,560  [628,572,160 .. 630,046,720)
    //   bsum  fp32  512          :       2,048  [630,046,720 .. 630,048,768)
    //   xb0/xb1 (fp32 32 x LSTR, 21,135,360 each) OVERLAY the skipc region:
    //   they are dead before the first GEMM chunk writes skipc (stream order).
    char* base = (char*)d_ws;
    __hip_bfloat16* Xcat = (__hip_bfloat16*)base;
    float* skipc = (float*)(base + 460800000);
    float* hc    = (float*)(base + 544686080);
    __hip_bfloat16* wcat = (__hip_bfloat16*)(base + 628572160);
    float* bsum  = (float*)(base + 630046720);
    float* xb0   = (float*)(base + 460800000);              // overlay on skipc
    float* xb1   = (float*)(base + 460800000 + 21135360);   // overlay on skipc
    const size_t need = 630048768;
    if (ws_size < need) {
        fprintf(stderr, "kernel_launch: ws_size %zu < needed %zu\n", ws_size, need);
        return;
    }

    repack_kernel<<<2880, 256, 0, stream>>>(w_skip, b_skip, wcat, bsum);
    causal_kernel<<<(L0 + 255) / 256, 256, 0, stream>>>(x, w_causal, b_causal, xb0);

    int Lin = L0;
    int S   = 2555;              // sum of all dilations
    float* xc = xb0;
    float* xn = xb1;
    for (int l = 0; l < NL; ++l) {
        const int d = 1 << (l % 9);
        const int Lout = Lin - 2 * d;
        S -= d;                  // S_l = sum of dilations after layer l
        gate_dense_kernel<<<(Lout + 255) / 256, 256, 0, stream>>>(
            xc, xn, Xcat + (size_t)l * 32 * FL,
            w_tanh + (size_t)l * 3072, w_sig + (size_t)l * 3072,
            w_dense + (size_t)l * 1024,
            b_tanh + l * 32, b_sig + l * 32, b_dense + l * 32,
            d, Lout, S);
        float* tmp = xc; xc = xn; xn = tmp;
        Lin = Lout;
    }

    // Downstream GEMMs chunked over the time axis: 1250 column-tiles total,
    // in chunks of <=320 tiles (CHUNKW=40960 columns) so skip/h stay fp32
    // within the workspace budget.
    const int totalTiles = 1250;
    for (int t0 = 0; t0 < totalTiles; t0 += 320) {
        const int tiles = (totalTiles - t0 < 320) ? (totalTiles - t0) : 320;
        const int n0 = t0 * 128;
        // skipc = Wcat @ Xcat[:, n0:n0+cw] + bsum   (512 x cw, K = 1440, bf16 in)
        gemm128<ushort_t, ushort_t, false, false><<<dim3(tiles, 4), 256, 0, stream>>>(
            (const ushort_t*)wcat, 1440, (const ushort_t*)Xcat + n0, FL,
            skipc, CHUNKW, bsum, 1440);
        // hc = relu(W1 @ relu(skipc) + b1)          (512 x cw, K = 512)
        gemm128<float, float, true, true><<<dim3(tiles, 4), 256, 0, stream>>>(
            w_post1, 512, skipc, CHUNKW, hc, CHUNKW, b_post1, 512);
        // out[:, n0:n0+cw] = W2 @ hc + b2           (256 x cw, K = 512)
        gemm128<float, float, false, false><<<dim3(tiles, 2), 256, 0, stream>>>(
            w_post2, 512, hc, CHUNKW, out + n0, FL, b_post2, 512);
    }
}

// Round 3
// 4459.463 us; speedup vs baseline: 2.0005x; 2.0005x over previous
//
#include <hip/hip_runtime.h>
#include <hip/hip_bf16.h>
#include <cstdio>

typedef unsigned short ushort_t;
typedef __bf16 bf16x8 __attribute__((ext_vector_type(8)));
typedef float f32x4 __attribute__((ext_vector_type(4)));

#define FL   160000      // final sequence length
#define L0   165110      // causal conv output length
#define LSTR 165120      // row stride for residual buffers (multiple of 64)
#define NL   45
#define CH   80000       // time-chunk for the GEMM chain (625 tiles of 128)

__device__ __forceinline__ float tanh_fast(float x) {
    float ax = fabsf(x);
    float e  = __expf(-2.f * ax);
    float r  = (1.f - e) / (1.f + e);
    return copysignf(r, x);
}

#define GLOAD_LDS16(gp, lp) \
    __builtin_amdgcn_global_load_lds( \
        (const __attribute__((address_space(1))) void*)(gp), \
        (__attribute__((address_space(3))) void*)(lp), 16, 0, 0)

// ---------------------------------------------------------------------------
// Causal conv: y[oc][t] = b[oc] + sum_k w[oc][k] * x[t+k],  t < L0
// ---------------------------------------------------------------------------
__global__ __launch_bounds__(256) void causal_kernel(
    const float* __restrict__ x, const float* __restrict__ wc,
    const float* __restrict__ bc, float* __restrict__ y)
{
    __shared__ float ws_[33 * 32];
    __shared__ float bs_[32];
    const int tid = threadIdx.x;
    for (int idx = tid; idx < 33 * 32; idx += 256) {
        int k = idx >> 5, oc = idx & 31;
        ws_[idx] = wc[oc * 33 + k];             // [k][oc]
    }
    if (tid < 32) bs_[tid] = bc[tid];
    __syncthreads();
    const int t = blockIdx.x * 256 + tid;
    if (t >= L0) return;
    float acc[32];
#pragma unroll
    for (int oc = 0; oc < 32; ++oc) acc[oc] = bs_[oc];
    for (int k = 0; k < 33; ++k) {
        float xv = x[t + k];
        const float* wp = &ws_[k * 32];
#pragma unroll
        for (int oc = 0; oc < 32; ++oc) acc[oc] += wp[oc] * xv;
    }
#pragma unroll
    for (int oc = 0; oc < 32; ++oc) y[(size_t)oc * LSTR + t] = acc[oc];
}

// ---------------------------------------------------------------------------
// Fused gate (tanh*sigmoid) + dense + residual.
// Writes the gated output bf16 into XcatT rows: XcatT[t][l*32+ic] (N x K).
// xslot points at XcatT + l*32; row stride 1440.
// ---------------------------------------------------------------------------
__global__ __launch_bounds__(256) void gate_dense_kernel(
    const float* __restrict__ xc, float* __restrict__ xn,
    __bf16* __restrict__ xslot,
    const float* __restrict__ wt, const float* __restrict__ wsg,
    const float* __restrict__ wd, const float* __restrict__ bt,
    const float* __restrict__ bs, const float* __restrict__ bd,
    int d, int Lout, int S)
{
    __shared__ float w8[32 * 32 * 8];   // [oc][ic][wt0,ws0,wt1,ws1,wt2,ws2,pad,pad]
    __shared__ float wds[1024];         // [oc][ic]
    __shared__ float bts[32], bss[32], bds[32];
    const int tid = threadIdx.x;
    for (int idx = tid; idx < 1024; idx += 256) {
        int g = idx * 3;                // (oc*32+ic)*3
        float* p = &w8[idx * 8];
        p[0] = wt[g];     p[1] = wsg[g];
        p[2] = wt[g + 1]; p[3] = wsg[g + 1];
        p[4] = wt[g + 2]; p[5] = wsg[g + 2];
        wds[idx] = wd[idx];
    }
    if (tid < 32) { bts[tid] = bt[tid]; bss[tid] = bs[tid]; bds[tid] = bd[tid]; }
    __syncthreads();
    const int t = blockIdx.x * 256 + tid;
    if (t >= Lout) return;

    float a[32], s[32];
#pragma unroll
    for (int oc = 0; oc < 32; ++oc) { a[oc] = bts[oc]; s[oc] = bss[oc]; }

    for (int ic = 0; ic < 32; ++ic) {
        const float* xr = xc + (size_t)ic * LSTR + t;
        float x0 = xr[0], x1 = xr[d], x2 = xr[2 * d];
        const float* wp = &w8[ic * 8];  // oc stride = 256 floats
#pragma unroll
        for (int oc = 0; oc < 32; ++oc) {
            const float4 w0 = *(const float4*)(wp + oc * 256);
            const float2 w1 = *(const float2*)(wp + oc * 256 + 4);
            a[oc] += w0.x * x0 + w0.z * x1 + w1.x * x2;
            s[oc] += w0.y * x0 + w0.w * x1 + w1.y * x2;
        }
    }
#pragma unroll
    for (int oc = 0; oc < 32; ++oc) {
        float th = tanh_fast(a[oc]);
        float sg = 1.f / (1.f + __expf(-s[oc]));
        a[oc] = th * sg;                // a[] now holds gated xg
    }
    if (t >= S && t < S + FL) {
        const int tw = t - S;
        __bf16 pk[32];
#pragma unroll
        for (int ic = 0; ic < 32; ++ic) pk[ic] = (__bf16)a[ic];
        uint4* dst = (uint4*)(xslot + (size_t)tw * 1440);
        const uint4* src = (const uint4*)pk;
#pragma unroll
        for (int j = 0; j < 4; ++j) dst[j] = src[j];
    }
#pragma unroll
    for (int oc = 0; oc < 32; ++oc) {
        float o = bds[oc] + xc[(size_t)oc * LSTR + t + d];
#pragma unroll
        for (int ic = 0; ic < 32; ++ic) o += wds[oc * 32 + ic] * a[ic];
        xn[(size_t)oc * LSTR + t] = o;
    }
}

// ---------------------------------------------------------------------------
// MFMA bf16 GEMM (m97 structure): C(MxN) = A(MxK) @ Bt(NxK)^T + bias.
// 128x128 tile, BK=32, 4 waves, 4x4 16x16x32 tiles/wave, global_load_lds.
// TSTORE=true : store relu(C)^T as bf16 at Cout[n*ldc + m]   (feeds next GEMM)
// TSTORE=false: store C as fp32 at Cout[m*ldc + n]           (final output)
// M = gridDim.y*128 (no bounds checks: all dims are exact multiples).
// ---------------------------------------------------------------------------
template<bool TSTORE>
__global__ __launch_bounds__(256) void gemm_mfma(
    const __bf16* __restrict__ A, int lda,
    const __bf16* __restrict__ Bt, int ldb,
    void* __restrict__ Cout, int ldc,
    const float* __restrict__ bias, int K)
{
    __shared__ __bf16 As[128 * 32];
    __shared__ __bf16 Bs[128 * 32];
    const int tid  = threadIdx.x;
    const int wave = tid >> 6, lane = tid & 63;
    const int m0 = blockIdx.y * 128, n0 = blockIdx.x * 128;
    const int mbase = (wave >> 1) * 64, nbase = (wave & 1) * 64;
    const int lrow = lane >> 2, lkc = (lane & 3) * 8;  // staging: row-in-16, 16B chunk
    const int fm = lane & 15, quad = lane >> 4;        // fragment row, k-quad

    f32x4 acc[4][4] = {};

    const int g0 = wave * 2, g1 = wave * 2 + 1;
    const __bf16* Ag0 = A  + (size_t)(m0 + g0 * 16 + lrow) * lda + lkc;
    const __bf16* Ag1 = A  + (size_t)(m0 + g1 * 16 + lrow) * lda + lkc;
    const __bf16* Bg0 = Bt + (size_t)(n0 + g0 * 16 + lrow) * ldb + lkc;
    const __bf16* Bg1 = Bt + (size_t)(n0 + g1 * 16 + lrow) * ldb + lkc;
    __bf16* lA0 = As + g0 * 512;    // 512 bf16 = 1024 B per wave-load
    __bf16* lA1 = As + g1 * 512;
    __bf16* lB0 = Bs + g0 * 512;
    __bf16* lB1 = Bs + g1 * 512;

    for (int k0 = 0; k0 < K; k0 += 32) {
        GLOAD_LDS16(Ag0 + k0, lA0);
        GLOAD_LDS16(Ag1 + k0, lA1);
        GLOAD_LDS16(Bg0 + k0, lB0);
        GLOAD_LDS16(Bg1 + k0, lB1);
        __syncthreads();               // compiler drains vmcnt before s_barrier
        bf16x8 af[4], bfr[4];
#pragma unroll
        for (int i = 0; i < 4; ++i)
            af[i] = *(const bf16x8*)(As + (mbase + i * 16 + fm) * 32 + quad * 8);
#pragma unroll
        for (int j = 0; j < 4; ++j)
            bfr[j] = *(const bf16x8*)(Bs + (nbase + j * 16 + fm) * 32 + quad * 8);
#pragma unroll
        for (int i = 0; i < 4; ++i)
#pragma unroll
            for (int j = 0; j < 4; ++j)
                acc[i][j] = __builtin_amdgcn_mfma_f32_16x16x32_bf16(
                    af[i], bfr[j], acc[i][j], 0, 0, 0);
        __syncthreads();               // protect LDS from next-iter overwrite
    }

    if (TSTORE) {
        __bf16* O = (__bf16*)Cout;
#pragma unroll
        for (int i = 0; i < 4; ++i) {
            const int m = m0 + mbase + i * 16 + quad * 4;
            const float4 bv = *(const float4*)(bias + m);
#pragma unroll
            for (int j = 0; j < 4; ++j) {
                const int n = n0 + nbase + j * 16 + fm;
                __bf16 pk[4];
                pk[0] = (__bf16)fmaxf(acc[i][j][0] + bv.x, 0.f);
                pk[1] = (__bf16)fmaxf(acc[i][j][1] + bv.y, 0.f);
                pk[2] = (__bf16)fmaxf(acc[i][j][2] + bv.z, 0.f);
                pk[3] = (__bf16)fmaxf(acc[i][j][3] + bv.w, 0.f);
                *(uint2*)(O + (size_t)n * ldc + m) = *(const uint2*)pk;
            }
        }
    } else {
        float* O = (float*)Cout;
#pragma unroll
        for (int i = 0; i < 4; ++i) {
            const int m = m0 + mbase + i * 16 + quad * 4;
            const float4 bv = *(const float4*)(bias + m);
#pragma unroll
            for (int j = 0; j < 4; ++j) {
                const int n = n0 + nbase + j * 16 + fm;
                O[(size_t)(m + 0) * ldc + n] = acc[i][j][0] + bv.x;
                O[(size_t)(m + 1) * ldc + n] = acc[i][j][1] + bv.y;
                O[(size_t)(m + 2) * ldc + n] = acc[i][j][2] + bv.z;
                O[(size_t)(m + 3) * ldc + n] = acc[i][j][3] + bv.w;
            }
        }
    }
}

// ---------------------------------------------------------------------------
// Repack skip weights to [oc][l*32+ic] bf16 and sum skip biases over layers.
// ---------------------------------------------------------------------------
__global__ __launch_bounds__(256) void repack_kernel(
    const float* __restrict__ wskip, const float* __restrict__ bskip,
    __bf16* __restrict__ wcat, float* __restrict__ bsum)
{
    const int idx = blockIdx.x * 256 + threadIdx.x;
    if (idx < 512 * 1440) {
        int oc = idx / 1440, lic = idx % 1440;
        int l = lic >> 5, ic = lic & 31;
        wcat[idx] = (__bf16)wskip[((size_t)l * 512 + oc) * 32 + ic];
    }
    if (idx < 512) {
        float s = 0.f;
        for (int l = 0; l < NL; ++l) s += bskip[l * 512 + idx];
        bsum[idx] = s;
    }
}

__global__ __launch_bounds__(256) void repack_post(
    const float* __restrict__ w1, const float* __restrict__ w2,
    __bf16* __restrict__ wp1, __bf16* __restrict__ wp2)
{
    const int idx = blockIdx.x * 256 + threadIdx.x;
    if (idx < 512 * 512) wp1[idx] = (__bf16)w1[idx];
    if (idx < 256 * 512) wp2[idx] = (__bf16)w2[idx];
}

extern "C" void kernel_launch(void* const* d_in, const int* in_sizes, int n_in,
                              void* d_out, int out_size, void* d_ws, size_t ws_size,
                              hipStream_t stream)
{
    const float* x        = (const float*)d_in[0];
    const float* w_causal = (const float*)d_in[1];
    const float* b_causal = (const float*)d_in[2];
    const float* w_tanh   = (const float*)d_in[3];
    const float* b_tanh   = (const float*)d_in[4];
    const float* w_sig    = (const float*)d_in[5];
    const float* b_sig    = (const float*)d_in[6];
    const float* w_skip   = (const float*)d_in[7];
    const float* b_skip   = (const float*)d_in[8];
    const float* w_dense  = (const float*)d_in[9];
    const float* b_dense  = (const float*)d_in[10];
    const float* w_post1  = (const float*)d_in[11];
    const float* b_post1  = (const float*)d_in[12];
    const float* w_post2  = (const float*)d_in[13];
    const float* b_post2  = (const float*)d_in[14];
    float* out = (float*)d_out;

    // Workspace carve (bytes). Budget: ws_size = 655,360,000.
    //   XcatT  bf16 [FL][1440]: 460,800,000  [0 .. 460,800,000)
    //   skipTc bf16 [CH][512] :  81,920,000  [460,800,000 .. 542,720,000)
    //   hTc    bf16 [CH][512] :  81,920,000  [542,720,000 .. 624,640,000)
    //   wcat   bf16 512x1440  :   1,474,560  [624,640,000 .. 626,114,560)
    //   wp1    bf16 512x512   :     524,288  [626,114,560 .. 626,638,848)
    //   wp2    bf16 256x512   :     262,144  [626,638,848 .. 626,900,992)
    //   bsum   fp32 512       :       2,048  [626,900,992 .. 626,903,040)
    //   xb0/xb1 (fp32 32xLSTR, 21,135,360 each) overlay skipTc (dead at GEMM time)
    char* base = (char*)d_ws;
    __bf16* XcatT  = (__bf16*)base;
    __bf16* skipTc = (__bf16*)(base + 460800000);
    __bf16* hTc    = (__bf16*)(base + 542720000);
    __bf16* wcat   = (__bf16*)(base + 624640000);
    __bf16* wp1    = (__bf16*)(base + 626114560);
    __bf16* wp2    = (__bf16*)(base + 626638848);
    float*  bsum   = (float*)(base + 626900992);
    float*  xb0    = (float*)(base + 460800000);
    float*  xb1    = (float*)(base + 460800000 + 21135360);
    const size_t need = 626903040;
    if (ws_size < need) {
        fprintf(stderr, "kernel_launch: ws_size %zu < needed %zu\n", ws_size, need);
        return;
    }

    repack_kernel<<<2880, 256, 0, stream>>>(w_skip, b_skip, wcat, bsum);
    repack_post<<<1024, 256, 0, stream>>>(w_post1, w_post2, wp1, wp2);
    causal_kernel<<<(L0 + 255) / 256, 256, 0, stream>>>(x, w_causal, b_causal, xb0);

    int Lin = L0;
    int S   = 2555;              // sum of all dilations
    float* xc = xb0;
    float* xn = xb1;
    for (int l = 0; l < NL; ++l) {
        const int d = 1 << (l % 9);
        const int Lout = Lin - 2 * d;
        S -= d;                  // S_l = sum of dilations after layer l
        gate_dense_kernel<<<(Lout + 255) / 256, 256, 0, stream>>>(
            xc, xn, XcatT + l * 32,
            w_tanh + (size_t)l * 3072, w_sig + (size_t)l * 3072,
            w_dense + (size_t)l * 1024,
            b_tanh + l * 32, b_sig + l * 32, b_dense + l * 32,
            d, Lout, S);
        float* tmp = xc; xc = xn; xn = tmp;
        Lin = Lout;
    }

    // GEMM chain, chunked x2 over time (625 tiles of 128 per chunk):
    for (int c = 0; c < 2; ++c) {
        const int c0 = c * CH;
        // skipTc^T = relu(Wcat @ XcatT^T + bsum), stored [t][oc] bf16
        gemm_mfma<true><<<dim3(CH / 128, 4), 256, 0, stream>>>(
            wcat, 1440, XcatT + (size_t)c0 * 1440, 1440, skipTc, 512, bsum, 1440);
        // hTc^T = relu(W1 @ skipTc^T + b1), stored [t][oc] bf16
        gemm_mfma<true><<<dim3(CH / 128, 4), 256, 0, stream>>>(
            wp1, 512, skipTc, 512, hTc, 512, b_post1, 512);
        // out[:, c0:c0+CH] = W2 @ hTc^T + b2, fp32 row-major
        gemm_mfma<false><<<dim3(CH / 128, 2), 256, 0, stream>>>(
            wp2, 512, hTc, 512, out + c0, FL, b_post2, 512);
    }
}

// Round 4
// 1930.918 us; speedup vs baseline: 4.6202x; 2.3095x over previous
//
#include <hip/hip_runtime.h>
#include <hip/hip_bf16.h>
#include <cstdio>

typedef unsigned short ushort_t;
typedef __bf16 bf16x8 __attribute__((ext_vector_type(8)));
typedef float f32x4 __attribute__((ext_vector_type(4)));

#define FL   160000      // final sequence length
#define L0   165110      // causal conv output length
#define NL   45
#define CH   80000       // time-chunk for the GEMM chain (625 tiles of 128)

__device__ __forceinline__ float tanh_fast(float x) {
    float ax = fabsf(x);
    float e  = __expf(-2.f * ax);
    float r  = (1.f - e) / (1.f + e);
    return copysignf(r, x);
}
__device__ __forceinline__ float sigmoid_fast(float x) {
    return 1.f / (1.f + __expf(-x));
}

#define GLOAD_LDS16(gp, lp) \
    __builtin_amdgcn_global_load_lds( \
        (const __attribute__((address_space(1))) void*)(gp), \
        (__attribute__((address_space(3))) void*)(lp), 16, 0, 0)

// ---------------------------------------------------------------------------
// Causal conv: y[t][oc] = b[oc] + sum_k w[oc][k] * x[t+k],  t < L0
// Output layout: fp32 [t][32] rows.
// ---------------------------------------------------------------------------
__global__ __launch_bounds__(256) void causal_kernel(
    const float* __restrict__ x, const float* __restrict__ wc,
    const float* __restrict__ bc, float* __restrict__ y)
{
    __shared__ float ws_[33 * 32];
    __shared__ float bs_[32];
    const int tid = threadIdx.x;
    for (int idx = tid; idx < 33 * 32; idx += 256) {
        int k = idx >> 5, oc = idx & 31;
        ws_[idx] = wc[oc * 33 + k];             // [k][oc]
    }
    if (tid < 32) bs_[tid] = bc[tid];
    __syncthreads();
    const int t = blockIdx.x * 256 + tid;
    if (t >= L0) return;
    float acc[32];
#pragma unroll
    for (int oc = 0; oc < 32; ++oc) acc[oc] = bs_[oc];
    for (int k = 0; k < 33; ++k) {
        float xv = x[t + k];
        const float* wp = &ws_[k * 32];
#pragma unroll
        for (int oc = 0; oc < 32; ++oc) acc[oc] += wp[oc] * xv;
    }
    float* yr = y + (size_t)t * 32;
#pragma unroll
    for (int oc = 0; oc < 32; oc += 4)
        *(float4*)(yr + oc) = make_float4(acc[oc], acc[oc+1], acc[oc+2], acc[oc+3]);
}

// ---------------------------------------------------------------------------
// Prepack conv (tanh+sig stacked, M=64, K=96=(tap,ic)) and dense (M=32,K=32)
// weights into MFMA A-fragment layout: frag[slot][lane][8],
// A[m = slot_m*16 + (lane&15)][k = (lane>>4)*8 + jj].
// fragConv: per layer 12 slots (tap*4 + mtile);  fragDense: 2 slots (mtile).
// ---------------------------------------------------------------------------
__global__ __launch_bounds__(256) void prepack_frag(
    const float* __restrict__ wt, const float* __restrict__ wsg,
    const float* __restrict__ wd,
    __bf16* __restrict__ fragConv, __bf16* __restrict__ fragDense)
{
    const int idx = blockIdx.x * 256 + threadIdx.x;
    if (idx < NL * 12 * 64) {
        const int lane = idx & 63;
        const int rem  = idx >> 6;
        const int slot = rem % 12, l = rem / 12;
        const int j = slot >> 2, i = slot & 3;        // tap, m-tile
        const int m = (i & 1) * 16 + (lane & 15);     // row within 32
        const int quad = lane >> 4;
        const float* wsrc = (i < 2) ? wt : wsg;
        __bf16 v[8];
#pragma unroll
        for (int jj = 0; jj < 8; ++jj) {
            int ic = quad * 8 + jj;
            v[jj] = (__bf16)wsrc[((size_t)(l * 32 + m) * 32 + ic) * 3 + j];
        }
        *(uint4*)(fragConv + (size_t)idx * 8) = *(const uint4*)v;
    }
    if (idx < NL * 2 * 64) {
        const int lane = idx & 63;
        const int rem  = idx >> 6;
        const int i = rem & 1, l = rem >> 1;
        const int m = i * 16 + (lane & 15);
        const int quad = lane >> 4;
        __bf16 v[8];
#pragma unroll
        for (int jj = 0; jj < 8; ++jj)
            v[jj] = (__bf16)wd[(size_t)(l * 32 + m) * 32 + quad * 8 + jj];
        *(uint4*)(fragDense + (size_t)idx * 8) = *(const uint4*)v;
    }
}

// ---------------------------------------------------------------------------
// Fully-fused MFMA layer: conv(tanh|sig) -> gate -> skip slab (bf16) +
// dense + residual (fp32). x layout [t][32] fp32. Wave-private LDS slab,
// no __syncthreads. Each wave owns 32 t's; block = 128 t's.
// ---------------------------------------------------------------------------
__global__ __launch_bounds__(256) void layer_mfma(
    const float* __restrict__ xin,   // [Lin][32] fp32, Lin = Lout + 2d
    float* __restrict__ xout,        // [Lout][32] fp32
    __bf16* __restrict__ xslot,      // XcatT + l*32, row stride 1440
    const __bf16* __restrict__ fragConv,   // layer's 12*64*8
    const __bf16* __restrict__ fragDense,  // layer's 2*64*8
    const float* __restrict__ bt, const float* __restrict__ bs,
    const float* __restrict__ bd,
    int d, int Lout, int S)
{
    __shared__ __bf16 gbuf[4][32][40];   // per-wave slab, ic padded 32->40
    const int tid  = threadIdx.x;
    const int wave = tid >> 6, lane = tid & 63;
    const int fm = lane & 15, quad = lane >> 4;
    const int t0 = blockIdx.x * 128 + wave * 32;

    // A fragments (uniform across waves, L1-hot)
    bf16x8 Ac[3][4], Ad[2];
#pragma unroll
    for (int j = 0; j < 3; ++j)
#pragma unroll
        for (int i = 0; i < 4; ++i)
            Ac[j][i] = *(const bf16x8*)(fragConv + ((j * 4 + i) * 64 + lane) * 8);
#pragma unroll
    for (int i = 0; i < 2; ++i)
        Ad[i] = *(const bf16x8*)(fragDense + (i * 64 + lane) * 8);

    // conv accumulators init with biases: m-tiles 0,1 = tanh rows, 2,3 = sig
    f32x4 acc[4][2];
#pragma unroll
    for (int i = 0; i < 4; ++i) {
        const float* bb = (i < 2) ? (bt + i * 16) : (bs + (i - 2) * 16);
        float4 b4 = *(const float4*)(bb + quad * 4);
        f32x4 bi; bi[0] = b4.x; bi[1] = b4.y; bi[2] = b4.z; bi[3] = b4.w;
        acc[i][0] = bi; acc[i][1] = bi;
    }

    // conv MFMAs: B built on the fly from fp32 x rows
#pragma unroll
    for (int j2 = 0; j2 < 2; ++j2) {
        int tl = t0 + j2 * 16 + fm;
        if (tl > Lout - 1) tl = Lout - 1;
#pragma unroll
        for (int j = 0; j < 3; ++j) {
            const float* xp = xin + (size_t)(tl + j * d) * 32 + quad * 8;
            float4 u0 = *(const float4*)xp;
            float4 u1 = *(const float4*)(xp + 4);
            bf16x8 bf;
            bf[0] = (__bf16)u0.x; bf[1] = (__bf16)u0.y;
            bf[2] = (__bf16)u0.z; bf[3] = (__bf16)u0.w;
            bf[4] = (__bf16)u1.x; bf[5] = (__bf16)u1.y;
            bf[6] = (__bf16)u1.z; bf[7] = (__bf16)u1.w;
#pragma unroll
            for (int i = 0; i < 4; ++i)
                acc[i][j2] = __builtin_amdgcn_mfma_f32_16x16x32_bf16(
                    Ac[j][i], bf, acc[i][j2], 0, 0, 0);
        }
    }

    // gate: g[ic][t] = tanh(z_t) * sigmoid(z_s); write to wave slab [t][ic]
#pragma unroll
    for (int i = 0; i < 2; ++i)
#pragma unroll
        for (int j2 = 0; j2 < 2; ++j2) {
            __bf16 pk[4];
#pragma unroll
            for (int r = 0; r < 4; ++r)
                pk[r] = (__bf16)(tanh_fast(acc[i][j2][r]) *
                                 sigmoid_fast(acc[i + 2][j2][r]));
            *(uint2*)&gbuf[wave][j2 * 16 + fm][i * 16 + quad * 4] =
                *(const uint2*)pk;
        }

    // skip slab: 64 B per t row -> XcatT[tw][l*32 .. +32), 32 B per lane
    {
        const int rr = lane >> 1, hh = lane & 1;
        const int t = t0 + rr, tw = t - S;
        if (t < Lout && (unsigned)tw < FL) {
            const char* gp = (const char*)&gbuf[wave][rr][0] + hh * 32;
            uint4 v0 = *(const uint4*)gp;
            uint4 v1 = *(const uint4*)(gp + 16);
            uint4* dst = (uint4*)(xslot + (size_t)tw * 1440 + hh * 16);
            dst[0] = v0; dst[1] = v1;
        }
    }

    // dense MFMA from slab + residual + fp32 store
    f32x4 dacc[2][2];
#pragma unroll
    for (int i = 0; i < 2; ++i) {
        float4 b4 = *(const float4*)(bd + i * 16 + quad * 4);
        f32x4 bi; bi[0] = b4.x; bi[1] = b4.y; bi[2] = b4.z; bi[3] = b4.w;
        dacc[i][0] = bi; dacc[i][1] = bi;
    }
#pragma unroll
    for (int j2 = 0; j2 < 2; ++j2) {
        bf16x8 gb = *(const bf16x8*)&gbuf[wave][j2 * 16 + fm][quad * 8];
#pragma unroll
        for (int i = 0; i < 2; ++i)
            dacc[i][j2] = __builtin_amdgcn_mfma_f32_16x16x32_bf16(
                Ad[i], gb, dacc[i][j2], 0, 0, 0);
    }
#pragma unroll
    for (int i = 0; i < 2; ++i)
#pragma unroll
        for (int j2 = 0; j2 < 2; ++j2) {
            const int t = t0 + j2 * 16 + fm;
            if (t < Lout) {
                const int oc = i * 16 + quad * 4;
                float4 r4 = *(const float4*)(xin + (size_t)(t + d) * 32 + oc);
                float4 o;
                o.x = dacc[i][j2][0] + r4.x;
                o.y = dacc[i][j2][1] + r4.y;
                o.z = dacc[i][j2][2] + r4.z;
                o.w = dacc[i][j2][3] + r4.w;
                *(float4*)(xout + (size_t)t * 32 + oc) = o;
            }
        }
}

// ---------------------------------------------------------------------------
// MFMA bf16 GEMM (m97 structure): C(MxN) = A(MxK) @ Bt(NxK)^T + bias.
// ---------------------------------------------------------------------------
template<bool TSTORE>
__global__ __launch_bounds__(256) void gemm_mfma(
    const __bf16* __restrict__ A, int lda,
    const __bf16* __restrict__ Bt, int ldb,
    void* __restrict__ Cout, int ldc,
    const float* __restrict__ bias, int K)
{
    __shared__ __bf16 As[128 * 32];
    __shared__ __bf16 Bs[128 * 32];
    const int tid  = threadIdx.x;
    const int wave = tid >> 6, lane = tid & 63;
    const int m0 = blockIdx.y * 128, n0 = blockIdx.x * 128;
    const int mbase = (wave >> 1) * 64, nbase = (wave & 1) * 64;
    const int lrow = lane >> 2, lkc = (lane & 3) * 8;
    const int fm = lane & 15, quad = lane >> 4;

    f32x4 acc[4][4] = {};

    const int g0 = wave * 2, g1 = wave * 2 + 1;
    const __bf16* Ag0 = A  + (size_t)(m0 + g0 * 16 + lrow) * lda + lkc;
    const __bf16* Ag1 = A  + (size_t)(m0 + g1 * 16 + lrow) * lda + lkc;
    const __bf16* Bg0 = Bt + (size_t)(n0 + g0 * 16 + lrow) * ldb + lkc;
    const __bf16* Bg1 = Bt + (size_t)(n0 + g1 * 16 + lrow) * ldb + lkc;
    __bf16* lA0 = As + g0 * 512;
    __bf16* lA1 = As + g1 * 512;
    __bf16* lB0 = Bs + g0 * 512;
    __bf16* lB1 = Bs + g1 * 512;

    for (int k0 = 0; k0 < K; k0 += 32) {
        GLOAD_LDS16(Ag0 + k0, lA0);
        GLOAD_LDS16(Ag1 + k0, lA1);
        GLOAD_LDS16(Bg0 + k0, lB0);
        GLOAD_LDS16(Bg1 + k0, lB1);
        __syncthreads();
        bf16x8 af[4], bfr[4];
#pragma unroll
        for (int i = 0; i < 4; ++i)
            af[i] = *(const bf16x8*)(As + (mbase + i * 16 + fm) * 32 + quad * 8);
#pragma unroll
        for (int j = 0; j < 4; ++j)
            bfr[j] = *(const bf16x8*)(Bs + (nbase + j * 16 + fm) * 32 + quad * 8);
#pragma unroll
        for (int i = 0; i < 4; ++i)
#pragma unroll
            for (int j = 0; j < 4; ++j)
                acc[i][j] = __builtin_amdgcn_mfma_f32_16x16x32_bf16(
                    af[i], bfr[j], acc[i][j], 0, 0, 0);
        __syncthreads();
    }

    if (TSTORE) {
        __bf16* O = (__bf16*)Cout;
#pragma unroll
        for (int i = 0; i < 4; ++i) {
            const int m = m0 + mbase + i * 16 + quad * 4;
            const float4 bv = *(const float4*)(bias + m);
#pragma unroll
            for (int j = 0; j < 4; ++j) {
                const int n = n0 + nbase + j * 16 + fm;
                __bf16 pk[4];
                pk[0] = (__bf16)fmaxf(acc[i][j][0] + bv.x, 0.f);
                pk[1] = (__bf16)fmaxf(acc[i][j][1] + bv.y, 0.f);
                pk[2] = (__bf16)fmaxf(acc[i][j][2] + bv.z, 0.f);
                pk[3] = (__bf16)fmaxf(acc[i][j][3] + bv.w, 0.f);
                *(uint2*)(O + (size_t)n * ldc + m) = *(const uint2*)pk;
            }
        }
    } else {
        float* O = (float*)Cout;
#pragma unroll
        for (int i = 0; i < 4; ++i) {
            const int m = m0 + mbase + i * 16 + quad * 4;
            const float4 bv = *(const float4*)(bias + m);
#pragma unroll
            for (int j = 0; j < 4; ++j) {
                const int n = n0 + nbase + j * 16 + fm;
                O[(size_t)(m + 0) * ldc + n] = acc[i][j][0] + bv.x;
                O[(size_t)(m + 1) * ldc + n] = acc[i][j][1] + bv.y;
                O[(size_t)(m + 2) * ldc + n] = acc[i][j][2] + bv.z;
                O[(size_t)(m + 3) * ldc + n] = acc[i][j][3] + bv.w;
            }
        }
    }
}

// ---------------------------------------------------------------------------
// Repack skip weights to [oc][l*32+ic] bf16 and sum skip biases over layers.
// ---------------------------------------------------------------------------
__global__ __launch_bounds__(256) void repack_kernel(
    const float* __restrict__ wskip, const float* __restrict__ bskip,
    __bf16* __restrict__ wcat, float* __restrict__ bsum)
{
    const int idx = blockIdx.x * 256 + threadIdx.x;
    if (idx < 512 * 1440) {
        int oc = idx / 1440, lic = idx % 1440;
        int l = lic >> 5, ic = lic & 31;
        wcat[idx] = (__bf16)wskip[((size_t)l * 512 + oc) * 32 + ic];
    }
    if (idx < 512) {
        float s = 0.f;
        for (int l = 0; l < NL; ++l) s += bskip[l * 512 + idx];
        bsum[idx] = s;
    }
}

__global__ __launch_bounds__(256) void repack_post(
    const float* __restrict__ w1, const float* __restrict__ w2,
    __bf16* __restrict__ wp1, __bf16* __restrict__ wp2)
{
    const int idx = blockIdx.x * 256 + threadIdx.x;
    if (idx < 512 * 512) wp1[idx] = (__bf16)w1[idx];
    if (idx < 256 * 512) wp2[idx] = (__bf16)w2[idx];
}

extern "C" void kernel_launch(void* const* d_in, const int* in_sizes, int n_in,
                              void* d_out, int out_size, void* d_ws, size_t ws_size,
                              hipStream_t stream)
{
    const float* x        = (const float*)d_in[0];
    const float* w_causal = (const float*)d_in[1];
    const float* b_causal = (const float*)d_in[2];
    const float* w_tanh   = (const float*)d_in[3];
    const float* b_tanh   = (const float*)d_in[4];
    const float* w_sig    = (const float*)d_in[5];
    const float* b_sig    = (const float*)d_in[6];
    const float* w_skip   = (const float*)d_in[7];
    const float* b_skip   = (const float*)d_in[8];
    const float* w_dense  = (const float*)d_in[9];
    const float* b_dense  = (const float*)d_in[10];
    const float* w_post1  = (const float*)d_in[11];
    const float* b_post1  = (const float*)d_in[12];
    const float* w_post2  = (const float*)d_in[13];
    const float* b_post2  = (const float*)d_in[14];
    float* out = (float*)d_out;

    // Workspace carve (bytes). Budget: ws_size = 655,360,000.
    //   XcatT    bf16 [FL][1440]: 460,800,000  [0 .. 460,800,000)
    //   skipTc   bf16 [CH][512] :  81,920,000  [460,800,000 .. 542,720,000)
    //   hTc      bf16 [CH][512] :  81,920,000  [542,720,000 .. 624,640,000)
    //   wcat     bf16 512x1440  :   1,474,560  [624,640,000 .. 626,114,560)
    //   wp1      bf16 512x512   :     524,288  [626,114,560 .. 626,638,848)
    //   wp2      bf16 256x512   :     262,144  [626,638,848 .. 626,900,992)
    //   bsum     fp32 512       :       2,048  [626,900,992 .. 626,903,040)
    //   fragConv bf16 45*12*512 :     552,960  [626,903,040 .. 627,456,000)
    //   fragDense bf16 45*2*512 :      92,160  [627,456,000 .. 627,548,160)
    //   xb0/xb1 (fp32 [L0][32], 21,135,360 each) overlay skipTc (dead at GEMM time)
    char* base = (char*)d_ws;
    __bf16* XcatT  = (__bf16*)base;
    __bf16* skipTc = (__bf16*)(base + 460800000);
    __bf16* hTc    = (__bf16*)(base + 542720000);
    __bf16* wcat   = (__bf16*)(base + 624640000);
    __bf16* wp1    = (__bf16*)(base + 626114560);
    __bf16* wp2    = (__bf16*)(base + 626638848);
    float*  bsum   = (float*)(base + 626900992);
    __bf16* fragConv  = (__bf16*)(base + 626903040);
    __bf16* fragDense = (__bf16*)(base + 627456000);
    float*  xb0    = (float*)(base + 460800000);
    float*  xb1    = (float*)(base + 460800000 + 21135360);
    const size_t need = 627548160;
    if (ws_size < need) {
        fprintf(stderr, "kernel_launch: ws_size %zu < needed %zu\n", ws_size, need);
        return;
    }

    repack_kernel<<<2880, 256, 0, stream>>>(w_skip, b_skip, wcat, bsum);
    repack_post<<<1024, 256, 0, stream>>>(w_post1, w_post2, wp1, wp2);
    prepack_frag<<<(NL * 12 * 64 + 255) / 256, 256, 0, stream>>>(
        w_tanh, w_sig, w_dense, fragConv, fragDense);
    causal_kernel<<<(L0 + 255) / 256, 256, 0, stream>>>(x, w_causal, b_causal, xb0);

    int Lin = L0;
    int S   = 2555;              // sum of all dilations
    float* xc = xb0;
    float* xn = xb1;
    for (int l = 0; l < NL; ++l) {
        const int d = 1 << (l % 9);
        const int Lout = Lin - 2 * d;
        S -= d;                  // S_l = skip-window start after layer l
        layer_mfma<<<(Lout + 127) / 128, 256, 0, stream>>>(
            xc, xn, XcatT + l * 32,
            fragConv + (size_t)l * 12 * 64 * 8,
            fragDense + (size_t)l * 2 * 64 * 8,
            b_tanh + l * 32, b_sig + l * 32, b_dense + l * 32,
            d, Lout, S);
        float* tmp = xc; xc = xn; xn = tmp;
        Lin = Lout;
    }

    // GEMM chain, chunked x2 over time (625 tiles of 128 per chunk):
    for (int c = 0; c < 2; ++c) {
        const int c0 = c * CH;
        // skipTc^T = relu(Wcat @ XcatT^T + bsum), stored [t][oc] bf16
        gemm_mfma<true><<<dim3(CH / 128, 4), 256, 0, stream>>>(
            wcat, 1440, XcatT + (size_t)c0 * 1440, 1440, skipTc, 512, bsum, 1440);
        // hTc^T = relu(W1 @ skipTc^T + b1), stored [t][oc] bf16
        gemm_mfma<true><<<dim3(CH / 128, 4), 256, 0, stream>>>(
            wp1, 512, skipTc, 512, hTc, 512, b_post1, 512);
        // out[:, c0:c0+CH] = W2 @ hTc^T + b2, fp32 row-major
        gemm_mfma<false><<<dim3(CH / 128, 2), 256, 0, stream>>>(
            wp2, 512, hTc, 512, out + c0, FL, b_post2, 512);
    }
}